// Round 1
// baseline (338.387 us; speedup 1.0000x reference)
//
#include <hip/hip_runtime.h>
#include <math.h>

#define NETS   64
#define NNODES 288
#define NHID   256
#define NOUT   32
#define NSTATE 386   // inputs(128) + const0 + const1 + hidden(256)
#define KCON   32
#define NBATCH 1024
#define TILE   32

// ---------------- prep: gathered weights Wg[net][node][k] = W[conn][node] ----------------
__global__ __launch_bounds__(256) void prep_wg(const float* __restrict__ W,
                                               const int* __restrict__ conn,
                                               float* __restrict__ Wg) {
    int g = blockIdx.x * 256 + threadIdx.x;          // exactly 64*288*32 threads
    int node = (g >> 5) % NNODES;
    Wg[g] = W[(size_t)conn[g] * NNODES + node];
}

// ---------------- prep: xT[input][batch] (transpose for coalesced LDS staging) ----------
__global__ __launch_bounds__(256) void prep_xt(const float* __restrict__ x,
                                               float* __restrict__ xT) {
    int g = blockIdx.x * 256 + threadIdx.x;          // 1024*128 threads
    int b = g >> 7, r = g & 127;
    xT[(size_t)r * NBATCH + b] = x[g];
}

// ---------------- main: sequential node evaluation, 1 wave / (net, 32-batch tile) -------
__global__ __launch_bounds__(64) void unn_main(const float* __restrict__ xT,
                                               const int* __restrict__ conn,
                                               const float* __restrict__ Wg,
                                               float* __restrict__ outs) {
    __shared__ float st[NSTATE * TILE];              // 49408 B -> 3 blocks/CU
    const int lane = threadIdx.x;
    const int half = lane >> 5;                      // k-half: 0 -> k 0..15, 1 -> k 16..31
    const int b    = lane & 31;                      // batch within tile
    const int net  = blockIdx.x >> 5;
    const int tile = blockIdx.x & 31;
    const int b0   = tile * TILE;

    // stage inputs: rows 0..127 = x, row 128 = 0, row 129 = 1
    for (int i = lane; i < 128 * TILE / 4; i += 64) {   // 16 iters of float4
        int row = i >> 3;
        int c4  = i & 7;
        float4 v = *(const float4*)(xT + (size_t)row * NBATCH + b0 + c4 * 4);
        *(float4*)(st + row * TILE + c4 * 4) = v;
    }
    if (lane < TILE) {
        st[128 * TILE + lane] = 0.0f;
        st[129 * TILE + lane] = 1.0f;
    }
    __syncthreads();

    const size_t base = (size_t)net * NNODES * KCON + half * 16;
    const int*   cp  = conn + base;
    const float* wp  = Wg   + base;
    const float* stb = st + b;

    int4   ic0, ic1, ic2, ic3, in0, in1, in2, in3;
    float4 wc0, wc1, wc2, wc3, wn0, wn1, wn2, wn3;

#define PREF(I0,I1,I2,I3,W0,W1,W2,W3, nd) {                               \
    const int4*   ip = (const int4*)(cp + (size_t)(nd) * KCON);           \
    const float4* fp = (const float4*)(wp + (size_t)(nd) * KCON);         \
    I0 = ip[0]; I1 = ip[1]; I2 = ip[2]; I3 = ip[3];                       \
    W0 = fp[0]; W1 = fp[1]; W2 = fp[2]; W3 = fp[3]; }

#define GATH(IV, WV)                                                      \
    a0 = fmaf(WV.x, stb[(IV).x << 5], a0);                                \
    a1 = fmaf(WV.y, stb[(IV).y << 5], a1);                                \
    a2 = fmaf(WV.z, stb[(IV).z << 5], a2);                                \
    a3 = fmaf(WV.w, stb[(IV).w << 5], a3);

#define BODY(I0,I1,I2,I3,W0,W1,W2,W3, nd) {                               \
    float a0 = 0.f, a1 = 0.f, a2 = 0.f, a3 = 0.f;                         \
    GATH(I0, W0) GATH(I1, W1) GATH(I2, W2) GATH(I3, W3)                   \
    float acc = (a0 + a1) + (a2 + a3);                                    \
    acc += __shfl_xor(acc, 32, 64);                                       \
    float act = fmaxf(acc, 0.01f * acc);                                  \
    if ((nd) < NHID) {                                                    \
        if (half == 0) st[(130 + (nd)) * TILE + b] = act;                 \
    } else {                                                              \
        if (half == 0)                                                    \
            outs[((size_t)net * NOUT + ((nd) - NHID)) * NBATCH + b0 + b] = act; \
    } }

    PREF(ic0,ic1,ic2,ic3,wc0,wc1,wc2,wc3, 0)
    for (int node = 0; node < NNODES; node += 2) {
        PREF(in0,in1,in2,in3,wn0,wn1,wn2,wn3, node + 1)
        BODY(ic0,ic1,ic2,ic3,wc0,wc1,wc2,wc3, node)
        int nd2 = (node + 2 < NNODES) ? node + 2 : NNODES - 1;
        PREF(ic0,ic1,ic2,ic3,wc0,wc1,wc2,wc3, nd2)
        BODY(in0,in1,in2,in3,wn0,wn1,wn2,wn3, node + 1)
    }
#undef PREF
#undef GATH
#undef BODY
}

// ---------------- reduce: out[b][o] = sum_n softmax(nw)[n] * outs[n][o][b] --------------
__global__ __launch_bounds__(64) void unn_reduce(const float* __restrict__ nw,
                                                 const float* __restrict__ outs,
                                                 float* __restrict__ out) {
    __shared__ float sw[NETS];
    __shared__ float tr[NOUT][65];
    int t = threadIdx.x;                             // 0..63
    float v = nw[t];
    float m = v;
    #pragma unroll
    for (int off = 32; off; off >>= 1) m = fmaxf(m, __shfl_xor(m, off, 64));
    float e = __expf(v - m);
    float s = e;
    #pragma unroll
    for (int off = 32; off; off >>= 1) s += __shfl_xor(s, off, 64);
    sw[t] = e / s;
    __syncthreads();

    int b0 = blockIdx.x * 64;
    for (int o = 0; o < NOUT; ++o) {
        float acc = 0.f;
        #pragma unroll 8
        for (int n = 0; n < NETS; ++n)
            acc = fmaf(sw[n], outs[((size_t)n * NOUT + o) * NBATCH + b0 + t], acc);
        tr[o][t] = acc;
    }
    __syncthreads();
    #pragma unroll
    for (int i = 0; i < 32; ++i) {
        int idx = t + 64 * i;                        // 0..2047
        int bb = idx >> 5, o = idx & 31;
        out[(size_t)(b0 + bb) * NOUT + o] = tr[o][bb];
    }
}

extern "C" void kernel_launch(void* const* d_in, const int* in_sizes, int n_in,
                              void* d_out, int out_size, void* d_ws, size_t ws_size,
                              hipStream_t stream) {
    const float* x    = (const float*)d_in[0];   // 1024*128
    const float* W    = (const float*)d_in[1];   // 386*288
    const float* nw   = (const float*)d_in[2];   // 64
    const int*   conn = (const int*)d_in[3];     // 64*288*32
    float* out = (float*)d_out;                  // 1024*32

    char* ws = (char*)d_ws;
    float* Wg   = (float*)(ws);                          // 2,359,296 B
    float* xT   = (float*)(ws + 2359296);                //   524,288 B
    float* outs = (float*)(ws + 2359296 + 524288);       // 8,388,608 B

    prep_wg <<<dim3((NETS*NNODES*KCON)/256), dim3(256), 0, stream>>>(W, conn, Wg);
    prep_xt <<<dim3((NBATCH*128)/256),       dim3(256), 0, stream>>>(x, xT);
    unn_main<<<dim3(NETS * (NBATCH/TILE)),   dim3(64),  0, stream>>>(xT, conn, Wg, outs);
    unn_reduce<<<dim3(NBATCH/64),            dim3(64),  0, stream>>>(nw, outs, out);
}

// Round 2
// 294.396 us; speedup vs baseline: 1.1494x; 1.1494x over previous
//
#include <hip/hip_runtime.h>
#include <math.h>

#define NETS   64
#define NNODES 288
#define NHID   256
#define NOUT   32
#define KCON   32
#define NBATCH 1024
#define TILE   32
#define WPB    4                       // nets (waves) per block, share input rows
#define NROWS  (130 + WPB * NHID)      // 1154 LDS rows of 32 floats = 147,712 B

#ifdef __has_builtin
#if __has_builtin(__builtin_amdgcn_permlane32_swap)
#define HAVE_PLSWAP 1
#endif
#endif

__device__ __forceinline__ float xor32_sum(float a) {
#ifdef HAVE_PLSWAP
    // swaps hi-half of arg0 with lo-half of arg1; with both = a:
    // r0 = {a.lo | a.lo}, r1 = {a.hi | a.hi}  ->  r0 + r1 = xor32 sum in all lanes
    auto r = __builtin_amdgcn_permlane32_swap(__float_as_uint(a), __float_as_uint(a),
                                              false, false);
    return __uint_as_float(r[0]) + __uint_as_float(r[1]);
#else
    return a + __shfl_xor(a, 32, 64);
#endif
}

// ---------------- prep: gathered weights Wg[net][node][k] = W[conn][node] ----------------
__global__ __launch_bounds__(256) void prep_wg(const float* __restrict__ W,
                                               const int* __restrict__ conn,
                                               float* __restrict__ Wg) {
    int g = blockIdx.x * 256 + threadIdx.x;          // 64*288*32 threads
    int node = (g >> 5) % NNODES;
    Wg[g] = W[(size_t)conn[g] * NNODES + node];
}

// ---------------- prep: xT[input][batch] ------------------------------------------------
__global__ __launch_bounds__(256) void prep_xt(const float* __restrict__ x,
                                               float* __restrict__ xT) {
    int g = blockIdx.x * 256 + threadIdx.x;          // 1024*128 threads
    int b = g >> 7, r = g & 127;
    xT[(size_t)r * NBATCH + b] = x[g];
}

// ---------------- main: 4 nets/block share input rows; 1 wave per net --------------------
__global__ __launch_bounds__(256) void unn_main(const float* __restrict__ xT,
                                                const int* __restrict__ conn,
                                                const float* __restrict__ Wg,
                                                float* __restrict__ outs) {
    extern __shared__ float st[];                    // [NROWS][TILE]
    const int t    = threadIdx.x;
    const int w    = t >> 6;                         // wave = net slot 0..3
    const int lane = t & 63;
    const int half = lane >> 5;                      // k-half
    const int b    = lane & 31;                      // batch within tile
    int bid = (int)blockIdx.x;
    bid = (bid & 7) * 64 + (bid >> 3);               // XCD swizzle (512 % 8 == 0)
    const int net  = (bid >> 5) * WPB + w;
    const int b0   = (bid & 31) * TILE;
    const int woff = w * NHID;                       // hidden-row offset for this wave

    // stage shared input rows 0..127 (float4, coalesced), rows 128/129 = const 0/1
    for (int i = t; i < 1024; i += 256) {
        int row = i >> 3, c4 = i & 7;
        float4 v = *(const float4*)(xT + (size_t)row * NBATCH + b0 + c4 * 4);
        *(float4*)(st + row * TILE + c4 * 4) = v;
    }
    if (t < 64) st[128 * TILE + t] = (t < 32) ? 0.0f : 1.0f;
    __syncthreads();
    // after this point waves are independent: shared rows are read-only,
    // each wave reads/writes only its own hidden rows (same-wave DS ops are in-order)

    const size_t base = (size_t)net * NNODES * KCON + half * 16;
    const int*   cp  = conn + base;
    const float* wp  = Wg   + base;
    const float* stb = st + b;
    float*       hw  = st + (size_t)(130 + woff) * TILE + b;
    float*       op  = outs + (size_t)net * NOUT * NBATCH + b0 + b;

    int4   ic0, ic1, ic2, ic3, in0, in1, in2, in3;
    float4 wc0, wc1, wc2, wc3, wn0, wn1, wn2, wn3;

#define ADJ4(IV) { (IV).x += ((IV).x >= 130) ? woff : 0;                  \
                   (IV).y += ((IV).y >= 130) ? woff : 0;                  \
                   (IV).z += ((IV).z >= 130) ? woff : 0;                  \
                   (IV).w += ((IV).w >= 130) ? woff : 0; }

#define PREF(I0,I1,I2,I3,W0,W1,W2,W3, nd) {                               \
    const int4*   ip = (const int4*)(cp + (size_t)(nd) * KCON);           \
    const float4* fp = (const float4*)(wp + (size_t)(nd) * KCON);         \
    I0 = ip[0]; I1 = ip[1]; I2 = ip[2]; I3 = ip[3];                       \
    W0 = fp[0]; W1 = fp[1]; W2 = fp[2]; W3 = fp[3];                       \
    ADJ4(I0) ADJ4(I1) ADJ4(I2) ADJ4(I3) }

#define GATH(IV, WV)                                                      \
    a0 = fmaf((WV).x, stb[(IV).x << 5], a0);                              \
    a1 = fmaf((WV).y, stb[(IV).y << 5], a1);                              \
    a2 = fmaf((WV).z, stb[(IV).z << 5], a2);                              \
    a3 = fmaf((WV).w, stb[(IV).w << 5], a3);

#define BODY(I0,I1,I2,I3,W0,W1,W2,W3, nd) {                               \
    float a0 = 0.f, a1 = 0.f, a2 = 0.f, a3 = 0.f;                         \
    GATH(I0, W0) GATH(I1, W1) GATH(I2, W2) GATH(I3, W3)                   \
    float acc = (a0 + a1) + (a2 + a3);                                    \
    acc = xor32_sum(acc);                                                 \
    float act = fmaxf(acc, 0.01f * acc);                                  \
    if ((nd) < NHID) hw[(nd) * TILE] = act;    /* both halves, same value */ \
    else if (half == 0) op[(size_t)((nd) - NHID) * NBATCH] = act; }

    PREF(ic0,ic1,ic2,ic3,wc0,wc1,wc2,wc3, 0)
    for (int node = 0; node < NNODES; node += 2) {
        PREF(in0,in1,in2,in3,wn0,wn1,wn2,wn3, node + 1)
        BODY(ic0,ic1,ic2,ic3,wc0,wc1,wc2,wc3, node)
        int nd2 = (node + 2 < NNODES) ? node + 2 : NNODES - 1;
        PREF(ic0,ic1,ic2,ic3,wc0,wc1,wc2,wc3, nd2)
        BODY(in0,in1,in2,in3,wn0,wn1,wn2,wn3, node + 1)
    }
#undef PREF
#undef GATH
#undef BODY
#undef ADJ4
}

// ---------------- reduce: out[b][o] = sum_n softmax(nw)[n] * outs[n][o][b] --------------
// grid: 512 blocks = (batch-tile 0..15) x (o 0..31), 64 threads
__global__ __launch_bounds__(64) void unn_reduce(const float* __restrict__ nw,
                                                 const float* __restrict__ outs,
                                                 float* __restrict__ out) {
    __shared__ float sw[NETS];
    int t  = threadIdx.x;
    int o  = blockIdx.x & 31;
    int bt = blockIdx.x >> 5;
    float v = nw[t];
    float m = v;
    #pragma unroll
    for (int off = 32; off; off >>= 1) m = fmaxf(m, __shfl_xor(m, off, 64));
    float e = __expf(v - m);
    float s = e;
    #pragma unroll
    for (int off = 32; off; off >>= 1) s += __shfl_xor(s, off, 64);
    sw[t] = e / s;
    __syncthreads();

    int bb = bt * 64 + t;
    float acc = 0.f;
    #pragma unroll 8
    for (int n = 0; n < NETS; ++n)
        acc = fmaf(sw[n], outs[((size_t)n * NOUT + o) * NBATCH + bb], acc);
    out[(size_t)bb * NOUT + o] = acc;
}

extern "C" void kernel_launch(void* const* d_in, const int* in_sizes, int n_in,
                              void* d_out, int out_size, void* d_ws, size_t ws_size,
                              hipStream_t stream) {
    const float* x    = (const float*)d_in[0];   // 1024*128
    const float* W    = (const float*)d_in[1];   // 386*288
    const float* nw   = (const float*)d_in[2];   // 64
    const int*   conn = (const int*)d_in[3];     // 64*288*32
    float* out = (float*)d_out;                  // 1024*32

    char* ws = (char*)d_ws;
    float* Wg   = (float*)(ws);                          // 2,359,296 B
    float* xT   = (float*)(ws + 2359296);                //   524,288 B
    float* outs = (float*)(ws + 2359296 + 524288);       // 8,388,608 B
                                                         // total 11,272,192 B (= round-1 usage)

    const int main_lds = NROWS * TILE * (int)sizeof(float);   // 147,712 B
    hipFuncSetAttribute(reinterpret_cast<const void*>(unn_main),
                        hipFuncAttributeMaxDynamicSharedMemorySize, main_lds);

    prep_wg <<<dim3((NETS*NNODES*KCON)/256), dim3(256), 0, stream>>>(W, conn, Wg);
    prep_xt <<<dim3((NBATCH*128)/256),       dim3(256), 0, stream>>>(x, xT);
    unn_main<<<dim3(NETS/WPB * 32),          dim3(256), main_lds, stream>>>(xT, conn, Wg, outs);
    unn_reduce<<<dim3(512),                  dim3(64),  0, stream>>>(nw, outs, out);
}

// Round 3
// 164.367 us; speedup vs baseline: 2.0587x; 1.7911x over previous
//
#include <hip/hip_runtime.h>
#include <math.h>

#define NETS   64
#define NNODES 288
#define NHID   256
#define NOUT   32
#define KCON   32
#define NBATCH 1024
#define TILE   32

#ifdef __has_builtin
#if __has_builtin(__builtin_amdgcn_permlane32_swap)
#define HAVE_PLSWAP 1
#endif
#endif

__device__ __forceinline__ float xor32_sum(float a) {
#ifdef HAVE_PLSWAP
    auto r = __builtin_amdgcn_permlane32_swap(__float_as_uint(a), __float_as_uint(a),
                                              false, false);
    return __uint_as_float(r[0]) + __uint_as_float(r[1]);
#else
    return a + __shfl_xor(a, 32, 64);
#endif
}

// ---------------- prep: gathered weights Wg[net][node][k] = W[conn][node] ----------------
__global__ __launch_bounds__(256) void prep_wg(const float* __restrict__ W,
                                               const int* __restrict__ conn,
                                               float* __restrict__ Wg) {
    int g = blockIdx.x * 256 + threadIdx.x;          // 64*288*32 threads
    int node = (g >> 5) % NNODES;
    Wg[g] = W[(size_t)conn[g] * NNODES + node];
}

// ---------------- prep: xT[input][batch] ------------------------------------------------
__global__ __launch_bounds__(256) void prep_xt(const float* __restrict__ x,
                                               float* __restrict__ xT) {
    int g = blockIdx.x * 256 + threadIdx.x;          // 1024*128 threads
    int b = g >> 7, r = g & 127;
    xT[(size_t)r * NBATCH + b] = x[g];
}

// ---------------- main: 1 wave / (net, 32-batch tile); node PAIRS (dep distance = 2) ----
// lane = kh(1b) | s(1b) | p(4b):  kh = k-half, s = node slot within pair, p = batch pair
__global__ __launch_bounds__(64) void unn_main(const float* __restrict__ xT,
                                               const int* __restrict__ conn,
                                               const float* __restrict__ Wg,
                                               float* __restrict__ outs) {
    __shared__ float st[(130 + NHID) * TILE];        // 386 rows x 32 f32 = 49,408 B
    const int lane = threadIdx.x;
    const int p    = lane & 15;                      // batch pair: batches 2p, 2p+1
    const int s    = (lane >> 4) & 1;                // node slot in pair
    const int kh   = lane >> 5;                      // k half: 0 -> k 0..15, 1 -> 16..31
    const int net  = blockIdx.x >> 5;
    const int b0   = (blockIdx.x & 31) * TILE;

    // stage inputs rows 0..127, consts rows 128 (0.0) / 129 (1.0)
    for (int i = lane; i < 128 * TILE / 4; i += 64) {
        int row = i >> 3, c4 = i & 7;
        float4 v = *(const float4*)(xT + (size_t)row * NBATCH + b0 + c4 * 4);
        *(float4*)(st + row * TILE + c4 * 4) = v;
    }
    if (lane < TILE) {
        st[128 * TILE + lane] = 0.0f;
        st[129 * TILE + lane] = 1.0f;
    }
    __syncthreads();

    // lane's slice of conn/Wg: node (nd+s), k-range [kh*16, kh*16+16)
    const size_t nb = (size_t)net * NNODES * KCON + s * KCON + kh * 16;
    const int*   cp  = conn + nb;
    const float* wp  = Wg   + nb;
    const float* stp = st + 2 * p;                   // this lane's batch-pair column

    int4   ic0, ic1, ic2, ic3, in0, in1, in2, in3;
    float4 wc0, wc1, wc2, wc3, wn0, wn1, wn2, wn3;

#define PREF(I0,I1,I2,I3,W0,W1,W2,W3, nd) {                               \
    const int4*   ip = (const int4*)(cp + (size_t)(nd) * KCON);           \
    const float4* fp = (const float4*)(wp + (size_t)(nd) * KCON);         \
    I0 = ip[0]; I1 = ip[1]; I2 = ip[2]; I3 = ip[3];                       \
    W0 = fp[0]; W1 = fp[1]; W2 = fp[2]; W3 = fp[3]; }

#define G1(ii, ww) { float2 v = *(const float2*)(stp + ((ii) << 5));      \
    ax = fmaf((ww), v.x, ax); ay = fmaf((ww), v.y, ay); }

#define GATH(IV, WV) G1((IV).x, (WV).x) G1((IV).y, (WV).y)                \
                     G1((IV).z, (WV).z) G1((IV).w, (WV).w)

#define BODY(I0,I1,I2,I3,W0,W1,W2,W3, nd) {                               \
    float ax = 0.f, ay = 0.f;                                             \
    GATH(I0, W0) GATH(I1, W1) GATH(I2, W2) GATH(I3, W3)                   \
    ax = xor32_sum(ax);                                                   \
    ay = xor32_sum(ay);                                                   \
    float vx = fmaxf(ax, 0.01f * ax);                                     \
    float vy = fmaxf(ay, 0.01f * ay);                                     \
    if (kh == 0) {                                                        \
        int node = (nd) + s;                                              \
        if ((nd) < NHID)                                                  \
            *(float2*)(st + (130 + node) * TILE + 2 * p) = make_float2(vx, vy); \
        else                                                              \
            *(float2*)(outs + ((size_t)net * NOUT + (node - NHID)) * NBATCH    \
                       + b0 + 2 * p) = make_float2(vx, vy);               \
    } }

    PREF(ic0,ic1,ic2,ic3,wc0,wc1,wc2,wc3, 0)
    for (int nd = 0; nd < NNODES; nd += 4) {
        PREF(in0,in1,in2,in3,wn0,wn1,wn2,wn3, nd + 2)
        BODY(ic0,ic1,ic2,ic3,wc0,wc1,wc2,wc3, nd)
        int nd2 = (nd + 4 < NNODES) ? nd + 4 : NNODES - 2;
        PREF(ic0,ic1,ic2,ic3,wc0,wc1,wc2,wc3, nd2)
        BODY(in0,in1,in2,in3,wn0,wn1,wn2,wn3, nd + 2)
    }
#undef PREF
#undef G1
#undef GATH
#undef BODY
}

// ---------------- reduce: out[b][o] = sum_n softmax(nw)[n] * outs[n][o][b] --------------
// grid: 512 blocks = (batch-tile 0..15) x (o 0..31), 64 threads
__global__ __launch_bounds__(64) void unn_reduce(const float* __restrict__ nw,
                                                 const float* __restrict__ outs,
                                                 float* __restrict__ out) {
    __shared__ float sw[NETS];
    int t  = threadIdx.x;
    int o  = blockIdx.x & 31;
    int bt = blockIdx.x >> 5;
    float v = nw[t];
    float m = v;
    #pragma unroll
    for (int off = 32; off; off >>= 1) m = fmaxf(m, __shfl_xor(m, off, 64));
    float e = __expf(v - m);
    float ssum = e;
    #pragma unroll
    for (int off = 32; off; off >>= 1) ssum += __shfl_xor(ssum, off, 64);
    sw[t] = e / ssum;
    __syncthreads();

    int bb = bt * 64 + t;
    float acc = 0.f;
    #pragma unroll 8
    for (int n = 0; n < NETS; ++n)
        acc = fmaf(sw[n], outs[((size_t)n * NOUT + o) * NBATCH + bb], acc);
    out[(size_t)bb * NOUT + o] = acc;
}

extern "C" void kernel_launch(void* const* d_in, const int* in_sizes, int n_in,
                              void* d_out, int out_size, void* d_ws, size_t ws_size,
                              hipStream_t stream) {
    const float* x    = (const float*)d_in[0];   // 1024*128
    const float* W    = (const float*)d_in[1];   // 386*288
    const float* nw   = (const float*)d_in[2];   // 64
    const int*   conn = (const int*)d_in[3];     // 64*288*32
    float* out = (float*)d_out;                  // 1024*32

    char* ws = (char*)d_ws;
    float* Wg   = (float*)(ws);                          // 2,359,296 B
    float* xT   = (float*)(ws + 2359296);                //   524,288 B
    float* outs = (float*)(ws + 2359296 + 524288);       // 8,388,608 B

    prep_wg <<<dim3((NETS*NNODES*KCON)/256), dim3(256), 0, stream>>>(W, conn, Wg);
    prep_xt <<<dim3((NBATCH*128)/256),       dim3(256), 0, stream>>>(x, xT);
    unn_main<<<dim3(NETS * (NBATCH/TILE)),   dim3(64),  0, stream>>>(xT, conn, Wg, outs);
    unn_reduce<<<dim3(512),                  dim3(64),  0, stream>>>(nw, outs, out);
}